// Round 9
// baseline (271.595 us; speedup 1.0000x reference)
//
#include <hip/hip_runtime.h>
#include <math.h>

#define NN   1200
#define EPSF 1e-8f

typedef _Float16 h8 __attribute__((ext_vector_type(8)));
typedef __attribute__((ext_vector_type(16))) float f16v;

// LDS plane byte offsets in kG staging buffer
#define AHI 0
#define ALO 16384
#define BHI 32768
#define BLO 49152

// ---- kA1: mean over k_shot + transpose -> supmean[b*125+s][c] fp32 ---------
__global__ __launch_bounds__(256) void kA1(const float* __restrict__ sxf,
                                           float* __restrict__ supmean) {
  const int blk = blockIdx.x;                    // b*25 + w*5 + ck
  const int b = blk / 25, rem = blk % 25, w = rem / 5, ck = rem % 5;
  const int c0 = ck * 128;
  const int tid = threadIdx.x;
  __shared__ float lds[3200];                    // [c_local(128)][j(25)]
  const float* base = sxf + (size_t)(b * 25 + w * 5) * 16000 + (size_t)c0 * 25;

  for (int f0 = tid * 4; f0 < 3200; f0 += 1024) {
    float4 a  = *(const float4*)(base + f0);
    float4 b1 = *(const float4*)(base + 16000 + f0);
    float4 c1 = *(const float4*)(base + 32000 + f0);
    float4 d1 = *(const float4*)(base + 48000 + f0);
    float4 e1 = *(const float4*)(base + 64000 + f0);
    lds[f0 + 0] = (a.x + b1.x + c1.x + d1.x + e1.x) * 0.2f;
    lds[f0 + 1] = (a.y + b1.y + c1.y + d1.y + e1.y) * 0.2f;
    lds[f0 + 2] = (a.z + b1.z + c1.z + d1.z + e1.z) * 0.2f;
    lds[f0 + 3] = (a.w + b1.w + c1.w + d1.w + e1.w) * 0.2f;
  }
  __syncthreads();
  for (int g = tid; g < 3200; g += 256) {
    int j = g >> 7, cc = g & 127;
    supmean[(size_t)(b * 125 + w * 25 + j) * 640 + c0 + cc] = lds[cc * 25 + j];
  }
}

// ---- kA2: normalize + f16 hi/lo split -> swizzled chunk layout -------------
// sup bytes: [b](320000) [ch=c/64](32000) [hl](16000) row s(128B): slot XOR (s&7)
__global__ __launch_bounds__(256) void kA2(const float* __restrict__ supmean,
                                           char* __restrict__ sup) {
  const int r = blockIdx.x * 4 + (threadIdx.x >> 6);    // 0..1999
  const int lane = threadIdx.x & 63;
  const int b = r / 125, s = r % 125;
  const float* row = supmean + (size_t)r * 640;
  float4 v0 = *(const float4*)(row + lane * 4);
  float4 v1 = *(const float4*)(row + 256 + lane * 4);
  float4 v2 = {0.f, 0.f, 0.f, 0.f};
  if (lane < 32) v2 = *(const float4*)(row + 512 + lane * 4);
  float ssq = v0.x*v0.x + v0.y*v0.y + v0.z*v0.z + v0.w*v0.w
            + v1.x*v1.x + v1.y*v1.y + v1.z*v1.z + v1.w*v1.w
            + v2.x*v2.x + v2.y*v2.y + v2.z*v2.z + v2.w*v2.w;
#pragma unroll
  for (int d = 32; d; d >>= 1) ssq += __shfl_xor(ssq, d);
  const float rinv = 1.f / (sqrtf(ssq) + EPSF);
  char* base = sup + (size_t)b * 320000;
#pragma unroll
  for (int seg = 0; seg < 3; ++seg) {
    if (seg == 2 && lane >= 32) break;
    float4 v = (seg == 0) ? v0 : ((seg == 1) ? v1 : v2);
    int c = seg * 256 + lane * 4;
    int ch = c >> 6, c64 = c & 63;
    int off = s * 128 + (((c64 >> 3) << 4) ^ ((s & 7) << 4)) + (c64 & 7) * 2;
    float vv[4] = { v.x * rinv, v.y * rinv, v.z * rinv, v.w * rinv };
    ushort hh[4], ll[4];
#pragma unroll
    for (int u = 0; u < 4; ++u) {
      _Float16 h = (_Float16)vv[u];
      _Float16 l = (_Float16)(vv[u] - (float)h);
      hh[u] = __builtin_bit_cast(ushort, h);
      ll[u] = __builtin_bit_cast(ushort, l);
    }
    uint2 ph = { (uint)hh[0] | ((uint)hh[1] << 16), (uint)hh[2] | ((uint)hh[3] << 16) };
    uint2 pl = { (uint)ll[0] | ((uint)ll[1] << 16), (uint)ll[2] | ((uint)ll[3] << 16) };
    *(uint2*)(base + ch * 32000 + off) = ph;
    *(uint2*)(base + ch * 32000 + 16000 + off) = pl;
  }
}

// ---- kG: fused GEMM (split-f16 MFMA) + softmaxes + Katz + loss -------------
__global__ __launch_bounds__(256, 1) void kG(const float* __restrict__ qxf,
                                             const int* __restrict__ qy,
                                             const char* __restrict__ sup,
                                             float* __restrict__ out) {
  const int blk = blockIdx.x;                 // b*15 + qg
  const int b = blk / 15, qg = blk % 15;
  const int tid = threadIdx.x;
  const int lane = tid & 63, l31 = lane & 31, hi32 = lane >> 5;
  const int wv = tid >> 6, wr = wv >> 1, wc = wv & 1;
  __shared__ __align__(16) char st[65536];    // staging planes; later S[125][128] f32
  __shared__ __align__(16) float TqsT[25 * 128];
  __shared__ float Bm[625];
  __shared__ float nsq[125], rinv_s[125], rhs[25], xv[25], Pk[5];

  const float* qbase5 = qxf + (size_t)(b * 75 + qg * 5) * 16000;
  const char*  supb   = sup + (size_t)b * 320000;

  // init: zero pad rows (bytes 16000..16383 of each plane), nsq, TqsT pad cols
  if (tid < 96) {
    uint4 z = {0u, 0u, 0u, 0u};
    *(uint4*)(st + (tid / 24) * 16384 + 16000 + (tid % 24) * 16) = z;
  }
  if (tid < 125) nsq[tid] = 0.f;
  if (tid >= 128 && tid < 203) {
    int k = tid - 128;
    TqsT[(k / 3) * 128 + 125 + (k % 3)] = 0.f;
  }

  f16v acc[2][2];
#pragma unroll
  for (int rt = 0; rt < 2; ++rt)
#pragma unroll
    for (int ct = 0; ct < 2; ++ct)
#pragma unroll
      for (int r = 0; r < 16; ++r) acc[rt][ct][r] = 0.f;

  float pn[8];
#pragma unroll
  for (int j = 0; j < 8; ++j) pn[j] = 0.f;

  for (int ch = 0; ch < 10; ++ch) {
    const int k0 = ch * 64;
    // B: async global->LDS, pre-swizzled source, linear dest (16B ops)
#pragma unroll
    for (int j = 0; j < 4; ++j) {
      int t = tid + j * 256;
      if (t < 1000) {
        const char* gh = supb + ch * 32000 + t * 16;
        __builtin_amdgcn_global_load_lds(
            (const __attribute__((address_space(1))) uint*)gh,
            (__attribute__((address_space(3))) uint*)(st + BHI + t * 16), 16, 0, 0);
        __builtin_amdgcn_global_load_lds(
            (const __attribute__((address_space(1))) uint*)(gh + 16000),
            (__attribute__((address_space(3))) uint*)(st + BLO + t * 16), 16, 0, 0);
      }
    }
    // A: load strided fp32, split f16 hi/lo, ds_write swizzled (no reg buffering)
#pragma unroll
    for (int j = 0; j < 8; ++j) {
      int t = tid + j * 256;
      if (t < 2000) {
        int q = t / 400, rem = t % 400, c4 = rem / 25, i = rem % 25;
        const float* qp = qbase5 + (size_t)q * 16000 + (size_t)(k0 + c4 * 4) * 25 + i;
        float w0 = qp[0], w1 = qp[25], w2 = qp[50], w3 = qp[75];
        pn[j] = fmaf(w0, w0, fmaf(w1, w1, fmaf(w2, w2, fmaf(w3, w3, pn[j]))));
        float vv[4] = { w0, w1, w2, w3 };
        ushort hh[4], ll[4];
#pragma unroll
        for (int u = 0; u < 4; ++u) {
          _Float16 h = (_Float16)vv[u];
          _Float16 l = (_Float16)(vv[u] - (float)h);
          hh[u] = __builtin_bit_cast(ushort, h);
          ll[u] = __builtin_bit_cast(ushort, l);
        }
        uint2 ph = { (uint)hh[0] | ((uint)hh[1] << 16), (uint)hh[2] | ((uint)hh[3] << 16) };
        uint2 pl = { (uint)ll[0] | ((uint)ll[1] << 16), (uint)ll[2] | ((uint)ll[3] << 16) };
        int r = q * 25 + i, c64 = c4 * 4;
        int off = r * 128 + (((c64 >> 3) << 4) ^ ((r & 7) << 4)) + (c64 & 7) * 2;
        *(uint2*)(st + AHI + off) = ph;
        *(uint2*)(st + ALO + off) = pl;
      }
    }
    __syncthreads();
#pragma unroll
    for (int ks = 0; ks < 4; ++ks) {
      const int kb = ks * 32 + hi32 * 16;
      h8 ahf[2], alf[2], bhf[2], blf[2];
#pragma unroll
      for (int rt = 0; rt < 2; ++rt) {
        int ar = wr * 64 + rt * 32 + l31;
        int off = ar * 128 + (kb ^ ((ar & 7) << 4));
        ahf[rt] = *(const h8*)(st + AHI + off);
        alf[rt] = *(const h8*)(st + ALO + off);
      }
#pragma unroll
      for (int ct = 0; ct < 2; ++ct) {
        int br = wc * 64 + ct * 32 + l31;
        int off = br * 128 + (kb ^ ((br & 7) << 4));
        bhf[ct] = *(const h8*)(st + BHI + off);
        blf[ct] = *(const h8*)(st + BLO + off);
      }
#pragma unroll
      for (int rt = 0; rt < 2; ++rt)
#pragma unroll
        for (int ct = 0; ct < 2; ++ct) {
          acc[rt][ct] = __builtin_amdgcn_mfma_f32_32x32x16_f16(ahf[rt], bhf[ct], acc[rt][ct], 0, 0, 0);
          acc[rt][ct] = __builtin_amdgcn_mfma_f32_32x32x16_f16(alf[rt], bhf[ct], acc[rt][ct], 0, 0, 0);
          acc[rt][ct] = __builtin_amdgcn_mfma_f32_32x32x16_f16(ahf[rt], blf[ct], acc[rt][ct], 0, 0, 0);
        }
    }
    __syncthreads();
  }

  // query norms -> rinv
#pragma unroll
  for (int j = 0; j < 8; ++j) {
    int t = tid + j * 256;
    if (t < 2000) {
      int q = t / 400, i = (t % 400) % 25;
      atomicAdd(&nsq[q * 25 + i], pn[j]);
    }
  }
  __syncthreads();
  if (tid < 125) rinv_s[tid] = 1.f / (sqrtf(nsq[tid]) + EPSF);
  __syncthreads();

  // S -> LDS (overwrites staging planes)
  float* S = (float*)st;                       // [125][128]
#pragma unroll
  for (int rt = 0; rt < 2; ++rt) {
#pragma unroll
    for (int r = 0; r < 16; ++r) {
      int rowg = wr * 64 + rt * 32 + (r & 3) + 8 * (r >> 2) + 4 * hi32;
      if (rowg < 125) {
        float rv = rinv_s[rowg];
#pragma unroll
        for (int ct = 0; ct < 2; ++ct) {
          int col = wc * 64 + ct * 32 + l31;
          S[rowg * 128 + col] = acc[rt][ct][r] * rv;
        }
      }
    }
  }
  __syncthreads();

  float lsum = 0.f;
  for (int q5 = 0; q5 < 5; ++q5) {
    float* Sq = S + q5 * 25 * 128;
    // phase 1: col softmax (gamma=10) -> TqsT; zero Pk
    if (tid < 125) {
      float mx = -1e30f;
#pragma unroll
      for (int i = 0; i < 25; ++i) mx = fmaxf(mx, Sq[i * 128 + tid]);
      float sm = 0.f;
      float ev[25];
#pragma unroll
      for (int i = 0; i < 25; ++i) { ev[i] = __expf(10.f * (Sq[i * 128 + tid] - mx)); sm += ev[i]; }
      float rs = 1.f / sm;
#pragma unroll
      for (int i = 0; i < 25; ++i) TqsT[i * 128 + tid] = ev[i] * rs;
    }
    if (tid >= 200 && tid < 205) Pk[tid - 200] = 0.f;
    __syncthreads();
    // phase 2: row softmax (gamma=20) in place
    if (tid < 200) {
      int i = tid >> 3, l = tid & 7;
      float* Srow = Sq + i * 128;
      float mx = -1e30f;
      for (int ss = l; ss < 125; ss += 8) mx = fmaxf(mx, Srow[ss]);
      mx = fmaxf(mx, __shfl_xor(mx, 1, 8));
      mx = fmaxf(mx, __shfl_xor(mx, 2, 8));
      mx = fmaxf(mx, __shfl_xor(mx, 4, 8));
      float sm = 0.f;
      for (int ss = l; ss < 128; ss += 8) {
        float e = 0.f;
        if (ss < 125) { e = __expf(20.f * (Srow[ss] - mx)); sm += e; }
        Srow[ss] = e;
      }
      sm += __shfl_xor(sm, 1, 8);
      sm += __shfl_xor(sm, 2, 8);
      sm += __shfl_xor(sm, 4, 8);
      float rs = 1.f / sm;
      for (int ss = l; ss < 125; ss += 8) Srow[ss] *= rs;
    }
    __syncthreads();
    // phase 3: Bm = TqsT . Tsq^T (K=128, pads zero) + rhs
    for (int ii = tid; ii < 625; ii += 256) {
      int i = ii / 25, ip = ii % 25;
      const float* ta = TqsT + i * 128;
      const float* tb = Sq + ip * 128;
      float4 s4 = { 0.f, 0.f, 0.f, 0.f };
#pragma unroll
      for (int q4 = 0; q4 < 32; ++q4) {
        float4 a4 = *(const float4*)(ta + q4 * 4);
        float4 b4 = *(const float4*)(tb + q4 * 4);
        s4.x = fmaf(a4.x, b4.x, s4.x); s4.y = fmaf(a4.y, b4.y, s4.y);
        s4.z = fmaf(a4.z, b4.z, s4.z); s4.w = fmaf(a4.w, b4.w, s4.w);
      }
      Bm[ii] = (s4.x + s4.y) + (s4.z + s4.w);
    }
    if (tid < 25) {
      const float* ta = TqsT + tid * 128;
      float4 s4 = { 0.f, 0.f, 0.f, 0.f };
#pragma unroll
      for (int q4 = 0; q4 < 32; ++q4) {
        float4 a4 = *(const float4*)(ta + q4 * 4);
        s4.x += a4.x; s4.y += a4.y; s4.z += a4.z; s4.w += a4.w;
      }
      rhs[tid] = 1.f + 0.5f * ((s4.x + s4.y) + (s4.z + s4.w));
    }
    __syncthreads();
    // phase 4: Jacobi (wave 0), x = rhs + 0.25 B x, 16 iters
    if (tid < 64) {
      float Brow[25], x, rh;
      if (tid < 25) {
        rh = rhs[tid]; x = rh;
#pragma unroll
        for (int ip = 0; ip < 25; ++ip) Brow[ip] = Bm[tid * 25 + ip];
      } else {
        rh = 0.f; x = 0.f;
#pragma unroll
        for (int ip = 0; ip < 25; ++ip) Brow[ip] = 0.f;
      }
#pragma unroll
      for (int it = 0; it < 16; ++it) {
        float sum = 0.f;
#pragma unroll
        for (int ip = 0; ip < 25; ++ip) sum = fmaf(Brow[ip], __shfl(x, ip), sum);
        x = rh + 0.25f * sum;
      }
      if (tid < 25) xv[tid] = x;
    }
    __syncthreads();
    // phase 5: katz -> class sums
    if (tid < 125) {
      float kz = 0.f;
#pragma unroll
      for (int i = 0; i < 25; ++i) kz = fmaf(Sq[i * 128 + tid], xv[i], kz);
      atomicAdd(&Pk[tid / 25], kz);
    }
    __syncthreads();
    // phase 6: loss term
    if (tid == 0) {
      float den = Pk[0] + Pk[1] + Pk[2] + Pk[3] + Pk[4];
      int y = qy[b * 75 + qg * 5 + q5];
      lsum += logf(den) - logf(Pk[y]);
    }
    __syncthreads();
  }
  if (tid == 0) atomicAdd(out, lsum * (1.0f / (float)NN));
}

extern "C" void kernel_launch(void* const* d_in, const int* in_sizes, int n_in,
                              void* d_out, int out_size, void* d_ws, size_t ws_size,
                              hipStream_t stream) {
  const float* sxf = (const float*)d_in[0];
  const float* qxf = (const float*)d_in[2];
  const int*   qy  = (const int*)d_in[3];
  float* out = (float*)d_out;
  float* supmean = (float*)d_ws;                       // 5.12 MB
  char*  sup     = (char*)d_ws + 5120000;              // 5.12 MB swizzled f16

  hipMemsetAsync(out, 0, sizeof(float), stream);
  kA1<<<400, 256, 0, stream>>>(sxf, supmean);
  kA2<<<500, 256, 0, stream>>>(supmean, sup);
  kG<<<240, 256, 0, stream>>>(qxf, qy, sup, out);
}